// Round 4
// baseline (167.046 us; speedup 1.0000x reference)
//
#include <hip/hip_runtime.h>
#include <math.h>

#define NN 100000
#define NE 500000

// ---------------------------------------------------------------------------
// Kernel 1: per-node projection, LDS-free.
//   AB[n][0:64]   = h[n] @ W1[0:128, :]   + b1      (source-role, b1 folded)
//   AB[n][64:128] = h[n] @ W1[128:256, :]           (target-role)
//
// Structure: lane = node. Each lane holds acc[128] (all outputs for its node)
// in VGPRs, statically indexed (fully unrolled j-loops). W is wave-uniform ->
// compiler emits s_load (SMEM pipe, W=64KB, L2-hot). h is lane-private float4
// global loads (each 64B line fully consumed; h read exactly once = 51.2 MB).
// No LDS, no barriers -> the 1.5x-oversubscribed LDS pipe of the tiled
// version (R1/R3: 31us LDS floor, 70us actual) disappears entirely.
// VALU floor: 16384 v_fmac/lane ~= 21 us machine-wide.
// ---------------------------------------------------------------------------
__global__ __launch_bounds__(256)
void node_proj(const float* __restrict__ h, const float* __restrict__ W1,
               const float* __restrict__ b1, float* __restrict__ AB, int nnodes)
{
    const int n = blockIdx.x * 256 + threadIdx.x;   // lane = node
    const bool valid = (n < nnodes);

    float acc[128];
    // init: fold b1 into the A-half (uniform loads -> s_load)
#pragma unroll
    for (int q = 0; q < 16; ++q) {
        float4 bv = *(const float4*)&b1[q * 4];
        acc[q * 4 + 0] = bv.x; acc[q * 4 + 1] = bv.y;
        acc[q * 4 + 2] = bv.z; acc[q * 4 + 3] = bv.w;
    }
#pragma unroll
    for (int j = 64; j < 128; ++j) acc[j] = 0.f;

    const float* hrow = h + (size_t)n * 128;
    float4 hv = valid ? *(const float4*)&hrow[0] : make_float4(0.f, 0.f, 0.f, 0.f);

#pragma unroll 1
    for (int k4 = 0; k4 < 32; ++k4) {
        // prefetch next h chunk (hides VMEM latency under the 512-FMA body)
        float4 hnext = (valid && k4 < 31) ? *(const float4*)&hrow[(k4 + 1) * 4]
                                          : make_float4(0.f, 0.f, 0.f, 0.f);
#pragma unroll
        for (int kk = 0; kk < 4; ++kk) {
            const int k = k4 * 4 + kk;
            // merged weight row: A-part = W1 row k, B-part = W1 row 128+k
            const float4* wa = (const float4*)(W1 + k * 64);          // uniform
            const float4* wb = (const float4*)(W1 + (128 + k) * 64);  // uniform
            const float hk = (kk == 0) ? hv.x : (kk == 1) ? hv.y
                           : (kk == 2) ? hv.z : hv.w;
#pragma unroll
            for (int q = 0; q < 16; ++q) {
                float4 w4 = wa[q];
                acc[q * 4 + 0] += hk * w4.x;
                acc[q * 4 + 1] += hk * w4.y;
                acc[q * 4 + 2] += hk * w4.z;
                acc[q * 4 + 3] += hk * w4.w;
            }
#pragma unroll
            for (int q = 0; q < 16; ++q) {
                float4 w4 = wb[q];
                acc[64 + q * 4 + 0] += hk * w4.x;
                acc[64 + q * 4 + 1] += hk * w4.y;
                acc[64 + q * 4 + 2] += hk * w4.z;
                acc[64 + q * 4 + 3] += hk * w4.w;
            }
        }
        hv = hnext;
    }

    if (valid) {
        float* orow = AB + (size_t)n * 128;
#pragma unroll
        for (int q = 0; q < 32; ++q) {
            float4 o = make_float4(acc[q * 4 + 0], acc[q * 4 + 1],
                                   acc[q * 4 + 2], acc[q * 4 + 3]);
            *(float4*)&orow[q * 4] = o;
        }
    }
}

// ---------------------------------------------------------------------------
// Kernel 2: per-edge sample. 16 lanes per edge; lane l owns hid[4l..4l+3].
// hid = relu(AB[row][0:64] + AB[col][64:128])   (b1 already folded into A)
// logits = hid @ W2 + b2 ;  weight = (logits + g1 > g0) ? 1 : 0
// ---------------------------------------------------------------------------
__global__ __launch_bounds__(256)
void edge_sample(const float* __restrict__ AB, const float* __restrict__ W2,
                 const float* __restrict__ b2, const float* __restrict__ u,
                 const int* __restrict__ ei, float* __restrict__ out)
{
    int t = threadIdx.x;
    int l = t & 15;
    int e = blockIdx.x * 16 + (t >> 4);

    int row = ei[e];
    int col = ei[NE + e];

    float4 a = *(const float4*)&AB[(size_t)row * 128 + l * 4];
    float4 b = *(const float4*)&AB[(size_t)col * 128 + 64 + l * 4];
    float4 w = *(const float4*)&W2[l * 4];

    float h0 = fmaxf(a.x + b.x, 0.f);
    float h1 = fmaxf(a.y + b.y, 0.f);
    float h2 = fmaxf(a.z + b.z, 0.f);
    float h3 = fmaxf(a.w + b.w, 0.f);

    float p = h0 * w.x + h1 * w.y + h2 * w.z + h3 * w.w;
    p += __shfl_xor(p, 1);
    p += __shfl_xor(p, 2);
    p += __shfl_xor(p, 4);
    p += __shfl_xor(p, 8);

    if (l == 0) {
        float logit = p + b2[0];
        float u0 = u[2 * e];
        float u1 = u[2 * e + 1];
        float g0 = -logf(-logf(u0));
        float g1 = -logf(-logf(u1));
        out[e]      = (logit + g1 > g0) ? 1.0f : 0.0f;  // argmax tie -> 0
        out[NE + e] = logit;
    }
}

// ---------------------------------------------------------------------------
// Fallback (only if ws_size too small): direct per-edge compute, correct but slow.
// ---------------------------------------------------------------------------
__global__ __launch_bounds__(256)
void edge_direct(const float* __restrict__ h, const float* __restrict__ W1,
                 const float* __restrict__ b1, const float* __restrict__ W2,
                 const float* __restrict__ b2, const float* __restrict__ u,
                 const int* __restrict__ ei, float* __restrict__ out)
{
    int t = threadIdx.x;
    int l = t & 15;
    int e = blockIdx.x * 16 + (t >> 4);

    int row = ei[e];
    int col = ei[NE + e];

    float a0 = 0.f, a1 = 0.f, a2 = 0.f, a3 = 0.f;
    const float* hr = h + (size_t)row * 128;
    const float* hc = h + (size_t)col * 128;

    for (int k4 = 0; k4 < 32; ++k4) {
        float4 hv = *(const float4*)&hr[k4 * 4];
#pragma unroll
        for (int kk = 0; kk < 4; ++kk) {
            float4 wr = *(const float4*)&W1[(k4 * 4 + kk) * 64 + l * 4];
            float hval = (&hv.x)[kk];
            a0 += hval * wr.x; a1 += hval * wr.y; a2 += hval * wr.z; a3 += hval * wr.w;
        }
    }
    for (int k4 = 0; k4 < 32; ++k4) {
        float4 hv = *(const float4*)&hc[k4 * 4];
#pragma unroll
        for (int kk = 0; kk < 4; ++kk) {
            float4 wr = *(const float4*)&W1[(128 + k4 * 4 + kk) * 64 + l * 4];
            float hval = (&hv.x)[kk];
            a0 += hval * wr.x; a1 += hval * wr.y; a2 += hval * wr.z; a3 += hval * wr.w;
        }
    }
    float4 bb = *(const float4*)&b1[l * 4];
    float4 w  = *(const float4*)&W2[l * 4];
    float h0 = fmaxf(a0 + bb.x, 0.f);
    float h1 = fmaxf(a1 + bb.y, 0.f);
    float h2 = fmaxf(a2 + bb.z, 0.f);
    float h3 = fmaxf(a3 + bb.w, 0.f);

    float p = h0 * w.x + h1 * w.y + h2 * w.z + h3 * w.w;
    p += __shfl_xor(p, 1);
    p += __shfl_xor(p, 2);
    p += __shfl_xor(p, 4);
    p += __shfl_xor(p, 8);

    if (l == 0) {
        float logit = p + b2[0];
        float u0 = u[2 * e];
        float u1 = u[2 * e + 1];
        float g0 = -logf(-logf(u0));
        float g1 = -logf(-logf(u1));
        out[e]      = (logit + g1 > g0) ? 1.0f : 0.0f;
        out[NE + e] = logit;
    }
}

extern "C" void kernel_launch(void* const* d_in, const int* in_sizes, int n_in,
                              void* d_out, int out_size, void* d_ws, size_t ws_size,
                              hipStream_t stream)
{
    const float* h  = (const float*)d_in[0];
    const float* W1 = (const float*)d_in[1];
    const float* b1 = (const float*)d_in[2];
    const float* W2 = (const float*)d_in[3];
    const float* b2 = (const float*)d_in[4];
    const float* u  = (const float*)d_in[5];
    const int*   ei = (const int*)d_in[6];
    float* out = (float*)d_out;

    const size_t need = (size_t)NN * 128 * sizeof(float);   // 51.2 MB
    if (ws_size >= need) {
        float* AB = (float*)d_ws;
        int nblocks = (NN + 255) / 256;                     // 391, all waves co-resident
        node_proj<<<nblocks, 256, 0, stream>>>(h, W1, b1, AB, NN);
        edge_sample<<<NE / 16, 256, 0, stream>>>(AB, W2, b2, u, ei, out);
    } else {
        edge_direct<<<NE / 16, 256, 0, stream>>>(h, W1, b1, W2, b2, u, ei, out);
    }
}

// Round 5
// 111.213 us; speedup vs baseline: 1.5020x; 1.5020x over previous
//
#include <hip/hip_runtime.h>
#include <math.h>

#define NN 100000
#define NE 500000

// ---------------------------------------------------------------------------
// Kernel 1: per-node projection.
//   AB[n][0:64]   = h[n] @ W1[0:128, :]   + b1      (source-role, b1 folded)
//   AB[n][64:128] = h[n] @ W1[128:256, :]           (target-role)
//
// Structure (R5): wave = 64 nodes (lane = node), each wave computes a
// 16-output j-slice -> acc[16] per lane (small, spill-proof).
// * W[k][j-slice] is wave-uniform (j-slice base derived via readfirstlane)
//   -> compiler emits s_load; FMAs are v_fmac_f32 vacc, s_w, v_h.
//   W leaves the LDS/VMEM pipes entirely (scalar pipe was idle).
// * h staged once per block into LDS (coalesced), read as one ds_read_b128
//   per lane per k4. Row stride 132 floats: within a 16-lane group banks
//   collide only 2-way (free, m136).
// Per k4 per wave: 64 FMA (128 cyc) vs 1 ds_read (12 cyc) -> LDS pipe at
// 4 blocks/CU is 2.7x under capacity (R1/R3's 8x8 tile had it 1.5x OVER).
// ---------------------------------------------------------------------------
__global__ __launch_bounds__(256)
void node_proj(const float* __restrict__ h, const float* __restrict__ W1,
               const float* __restrict__ b1, float* __restrict__ AB, int nnodes)
{
    __shared__ float lh[64 * 132];   // 33 KB: 64 nodes x 128 k, stride 132

    const int t  = threadIdx.x;
    const int g  = blockIdx.x >> 1;      // node group (64 nodes)
    const int jh = blockIdx.x & 1;       // j half (0: outputs 0..63, 1: 64..127)
    const int n0 = g * 64;

    // ---- stage h tile: 64 nodes x 128 k, fully coalesced global reads ----
#pragma unroll
    for (int i = 0; i < 8; ++i) {
        int flat = i * 256 + t;          // 0..2047
        int nl = flat >> 5;              // node 0..63
        int c  = flat & 31;              // float4 chunk 0..31
        int ng = n0 + nl;
        float4 v = make_float4(0.f, 0.f, 0.f, 0.f);
        if (ng < nnodes) v = *(const float4*)&h[(size_t)ng * 128 + c * 4];
        *(float4*)&lh[nl * 132 + c * 4] = v;
    }
    __syncthreads();

    const int wid  = __builtin_amdgcn_readfirstlane(t >> 6);  // 0..3, uniform
    const int lane = t & 63;
    const int jq   = jh * 64 + wid * 16;     // output slice base (uniform)

    // merged weight: out j<64 -> W1 rows 0..127 col j ; out j>=64 -> rows 128..255 col j-64
    const float* Wbase = (jq < 64) ? (W1 + jq) : (W1 + 128 * 64 + (jq - 64));

    float acc[16];
#pragma unroll
    for (int i = 0; i < 16; ++i) acc[i] = (jq < 64) ? b1[jq + i] : 0.f;

    const int lbase = lane * 132;

#pragma unroll 2
    for (int k4 = 0; k4 < 32; ++k4) {
        float4 hv = *(const float4*)&lh[lbase + k4 * 4];
#pragma unroll
        for (int kk = 0; kk < 4; ++kk) {
            const float* wr = Wbase + (k4 * 4 + kk) * 64;   // uniform address
            float hk = (kk == 0) ? hv.x : (kk == 1) ? hv.y
                     : (kk == 2) ? hv.z : hv.w;
#pragma unroll
            for (int q = 0; q < 4; ++q) {
                float4 w4 = *(const float4*)&wr[q * 4];
                acc[q * 4 + 0] += hk * w4.x;
                acc[q * 4 + 1] += hk * w4.y;
                acc[q * 4 + 2] += hk * w4.z;
                acc[q * 4 + 3] += hk * w4.w;
            }
        }
    }

    const int n = n0 + lane;
    if (n < nnodes) {
        float* orow = AB + (size_t)n * 128 + jq;
#pragma unroll
        for (int q = 0; q < 4; ++q)
            *(float4*)&orow[q * 4] = make_float4(acc[q * 4 + 0], acc[q * 4 + 1],
                                                 acc[q * 4 + 2], acc[q * 4 + 3]);
    }
}

// ---------------------------------------------------------------------------
// Kernel 2: per-edge sample. 16 lanes per edge; lane l owns hid[4l..4l+3].
// hid = relu(AB[row][0:64] + AB[col][64:128])   (b1 already folded into A)
// logits = hid @ W2 + b2 ;  weight = (logits + g1 > g0) ? 1 : 0
// ---------------------------------------------------------------------------
__global__ __launch_bounds__(256)
void edge_sample(const float* __restrict__ AB, const float* __restrict__ W2,
                 const float* __restrict__ b2, const float* __restrict__ u,
                 const int* __restrict__ ei, float* __restrict__ out)
{
    int t = threadIdx.x;
    int l = t & 15;
    int e = blockIdx.x * 16 + (t >> 4);

    int row = ei[e];
    int col = ei[NE + e];

    float4 a = *(const float4*)&AB[(size_t)row * 128 + l * 4];
    float4 b = *(const float4*)&AB[(size_t)col * 128 + 64 + l * 4];
    float4 w = *(const float4*)&W2[l * 4];

    float h0 = fmaxf(a.x + b.x, 0.f);
    float h1 = fmaxf(a.y + b.y, 0.f);
    float h2 = fmaxf(a.z + b.z, 0.f);
    float h3 = fmaxf(a.w + b.w, 0.f);

    float p = h0 * w.x + h1 * w.y + h2 * w.z + h3 * w.w;
    p += __shfl_xor(p, 1);
    p += __shfl_xor(p, 2);
    p += __shfl_xor(p, 4);
    p += __shfl_xor(p, 8);

    if (l == 0) {
        float logit = p + b2[0];
        float u0 = u[2 * e];
        float u1 = u[2 * e + 1];
        float g0 = -logf(-logf(u0));
        float g1 = -logf(-logf(u1));
        out[e]      = (logit + g1 > g0) ? 1.0f : 0.0f;  // argmax tie -> 0
        out[NE + e] = logit;
    }
}

// ---------------------------------------------------------------------------
// Fallback (only if ws_size too small): direct per-edge compute, correct but slow.
// ---------------------------------------------------------------------------
__global__ __launch_bounds__(256)
void edge_direct(const float* __restrict__ h, const float* __restrict__ W1,
                 const float* __restrict__ b1, const float* __restrict__ W2,
                 const float* __restrict__ b2, const float* __restrict__ u,
                 const int* __restrict__ ei, float* __restrict__ out)
{
    int t = threadIdx.x;
    int l = t & 15;
    int e = blockIdx.x * 16 + (t >> 4);

    int row = ei[e];
    int col = ei[NE + e];

    float a0 = 0.f, a1 = 0.f, a2 = 0.f, a3 = 0.f;
    const float* hr = h + (size_t)row * 128;
    const float* hc = h + (size_t)col * 128;

    for (int k4 = 0; k4 < 32; ++k4) {
        float4 hv = *(const float4*)&hr[k4 * 4];
#pragma unroll
        for (int kk = 0; kk < 4; ++kk) {
            float4 wr = *(const float4*)&W1[(k4 * 4 + kk) * 64 + l * 4];
            float hval = (&hv.x)[kk];
            a0 += hval * wr.x; a1 += hval * wr.y; a2 += hval * wr.z; a3 += hval * wr.w;
        }
    }
    for (int k4 = 0; k4 < 32; ++k4) {
        float4 hv = *(const float4*)&hc[k4 * 4];
#pragma unroll
        for (int kk = 0; kk < 4; ++kk) {
            float4 wr = *(const float4*)&W1[(128 + k4 * 4 + kk) * 64 + l * 4];
            float hval = (&hv.x)[kk];
            a0 += hval * wr.x; a1 += hval * wr.y; a2 += hval * wr.z; a3 += hval * wr.w;
        }
    }
    float4 bb = *(const float4*)&b1[l * 4];
    float4 w  = *(const float4*)&W2[l * 4];
    float h0 = fmaxf(a0 + bb.x, 0.f);
    float h1 = fmaxf(a1 + bb.y, 0.f);
    float h2 = fmaxf(a2 + bb.z, 0.f);
    float h3 = fmaxf(a3 + bb.w, 0.f);

    float p = h0 * w.x + h1 * w.y + h2 * w.z + h3 * w.w;
    p += __shfl_xor(p, 1);
    p += __shfl_xor(p, 2);
    p += __shfl_xor(p, 4);
    p += __shfl_xor(p, 8);

    if (l == 0) {
        float logit = p + b2[0];
        float u0 = u[2 * e];
        float u1 = u[2 * e + 1];
        float g0 = -logf(-logf(u0));
        float g1 = -logf(-logf(u1));
        out[e]      = (logit + g1 > g0) ? 1.0f : 0.0f;
        out[NE + e] = logit;
    }
}

extern "C" void kernel_launch(void* const* d_in, const int* in_sizes, int n_in,
                              void* d_out, int out_size, void* d_ws, size_t ws_size,
                              hipStream_t stream)
{
    const float* h  = (const float*)d_in[0];
    const float* W1 = (const float*)d_in[1];
    const float* b1 = (const float*)d_in[2];
    const float* W2 = (const float*)d_in[3];
    const float* b2 = (const float*)d_in[4];
    const float* u  = (const float*)d_in[5];
    const int*   ei = (const int*)d_in[6];
    float* out = (float*)d_out;

    const size_t need = (size_t)NN * 128 * sizeof(float);   // 51.2 MB
    if (ws_size >= need) {
        float* AB = (float*)d_ws;
        int ngroups = (NN + 63) / 64;                        // 1563
        node_proj<<<ngroups * 2, 256, 0, stream>>>(h, W1, b1, AB, NN);
        edge_sample<<<NE / 16, 256, 0, stream>>>(AB, W2, b2, u, ei, out);
    } else {
        edge_direct<<<NE / 16, 256, 0, stream>>>(h, W1, b1, W2, b2, u, ei, out);
    }
}

// Round 6
// 98.037 us; speedup vs baseline: 1.7039x; 1.1344x over previous
//
#include <hip/hip_runtime.h>
#include <math.h>

#define NN 100000
#define NE 500000

// ---------------------------------------------------------------------------
// Kernel 1: per-node projection.
//   AB[n][0:64]   = h[n] @ W1[0:128, :]   + b1      (source-role, b1 folded)
//   AB[n][64:128] = h[n] @ W1[128:256, :]           (target-role)
//
// R6 structure: split the two operand streams across two pipes.
//   * h  -> LDS (staged once, 128 nodes x 128 k, stride 133: the 4 tnf
//           broadcast groups land on banks 0/16/0/16 -> 2-way = free).
//           8 ds_read_b128 per wave per k4 = 384 LDS-pipe cyc/CU < 512 VALU.
//   * W  -> VMEM (global, 128 KB, L1/L2-hot), double-buffered in VGPRs,
//           hand-unrolled k4 step 2 (static buffer indexing, rule #20).
//           vmcnt is separate from lgkmcnt -> prefetch stays in flight
//           across the FMA body (R5's SGPR path shared lgkmcnt with DS and
//           full-drained every k4; SGPR file too small to double-buffer).
// acc 64 + Wbuf 64 + hv 32 + addr ~ 180 VGPR < 256 cap (no min-waves clause
// -> compiler won't spill; R2 lesson).
// ---------------------------------------------------------------------------
__global__ __launch_bounds__(256)
void node_proj(const float* __restrict__ h, const float* __restrict__ W1,
               const float* __restrict__ b1, float* __restrict__ AB, int nnodes)
{
    __shared__ float lh[128 * 133];   // 68 KB -> 2 blocks/CU (LDS), matches 2 waves/SIMD (VGPR)

    const int t   = threadIdx.x;
    const int tj  = t & 15;      // j-quad: A outputs tj*4..+3, B outputs 64+tj*4..+3
    const int tnf = t >> 4;      // node rows tnf + 16*r
    const int n0  = blockIdx.x * 128;

    // ---- stage h tile once: 128 nodes x 128 k, fully coalesced ----
#pragma unroll
    for (int i = 0; i < 16; ++i) {
        int flat = i * 256 + t;       // 0..4095
        int nl = flat >> 5;           // 0..127
        int c  = flat & 31;           // float4 chunk
        int ng = n0 + nl;
        float4 v = make_float4(0.f, 0.f, 0.f, 0.f);
        if (ng < nnodes) v = *(const float4*)&h[(size_t)ng * 128 + c * 4];
        *(float4*)&lh[nl * 133 + c * 4] = v;
    }
    __syncthreads();

    const float* wa_base = W1 + tj * 4;              // A: W1[k][tj*4..]
    const float* wb_base = W1 + 128 * 64 + tj * 4;   // B: W1[128+k][tj*4..]

    float acc[8][8];
    {
        float4 bv = *(const float4*)&b1[tj * 4];
#pragma unroll
        for (int r = 0; r < 8; ++r) {
            acc[r][0] = bv.x; acc[r][1] = bv.y; acc[r][2] = bv.z; acc[r][3] = bv.w;
            acc[r][4] = 0.f;  acc[r][5] = 0.f;  acc[r][6] = 0.f;  acc[r][7] = 0.f;
        }
    }

    // W double buffers (named -> static indexing, no scratch)
    float4 A0[4], B0[4], A1[4], B1[4];
#pragma unroll
    for (int kk = 0; kk < 4; ++kk) {
        A0[kk] = *(const float4*)&wa_base[kk * 64];
        B0[kk] = *(const float4*)&wb_base[kk * 64];
    }

#define LOAD_W(AX, BX, K4)                                              \
    _Pragma("unroll")                                                   \
    for (int kk = 0; kk < 4; ++kk) {                                    \
        AX[kk] = *(const float4*)&wa_base[((K4) * 4 + kk) * 64];        \
        BX[kk] = *(const float4*)&wb_base[((K4) * 4 + kk) * 64];        \
    }

#define COMPUTE(AX, BX, K4)                                             \
    {                                                                   \
        float4 hv[8];                                                   \
        _Pragma("unroll")                                               \
        for (int r = 0; r < 8; ++r)                                     \
            hv[r] = *(const float4*)&lh[(tnf + 16 * r) * 133 + (K4) * 4]; \
        _Pragma("unroll")                                               \
        for (int kk = 0; kk < 4; ++kk) {                                \
            float4 wa = AX[kk], wb = BX[kk];                            \
            _Pragma("unroll")                                           \
            for (int r = 0; r < 8; ++r) {                               \
                float hk = (kk == 0) ? hv[r].x : (kk == 1) ? hv[r].y    \
                         : (kk == 2) ? hv[r].z : hv[r].w;               \
                acc[r][0] += hk * wa.x;                                 \
                acc[r][1] += hk * wa.y;                                 \
                acc[r][2] += hk * wa.z;                                 \
                acc[r][3] += hk * wa.w;                                 \
                acc[r][4] += hk * wb.x;                                 \
                acc[r][5] += hk * wb.y;                                 \
                acc[r][6] += hk * wb.z;                                 \
                acc[r][7] += hk * wb.w;                                 \
            }                                                           \
        }                                                               \
    }

#pragma unroll 1
    for (int k4 = 0; k4 < 30; k4 += 2) {
        LOAD_W(A1, B1, k4 + 1)        // prefetch next while computing current
        COMPUTE(A0, B0, k4)
        LOAD_W(A0, B0, k4 + 2)
        COMPUTE(A1, B1, k4 + 1)
    }
    LOAD_W(A1, B1, 31)
    COMPUTE(A0, B0, 30)
    COMPUTE(A1, B1, 31)

#undef LOAD_W
#undef COMPUTE

    // ---- store: A-half at [0:64], B-half at [64:128] ----
#pragma unroll
    for (int r = 0; r < 8; ++r) {
        int ng = n0 + tnf + 16 * r;
        if (ng >= nnodes) continue;
        float* orow = AB + (size_t)ng * 128;
        *(float4*)&orow[tj * 4]      = make_float4(acc[r][0], acc[r][1], acc[r][2], acc[r][3]);
        *(float4*)&orow[64 + tj * 4] = make_float4(acc[r][4], acc[r][5], acc[r][6], acc[r][7]);
    }
}

// ---------------------------------------------------------------------------
// Kernel 2: per-edge sample. 16 lanes per edge; lane l owns hid[4l..4l+3].
// hid = relu(AB[row][0:64] + AB[col][64:128])   (b1 already folded into A)
// logits = hid @ W2 + b2 ;  weight = (logits + g1 > g0) ? 1 : 0
// ---------------------------------------------------------------------------
__global__ __launch_bounds__(256)
void edge_sample(const float* __restrict__ AB, const float* __restrict__ W2,
                 const float* __restrict__ b2, const float* __restrict__ u,
                 const int* __restrict__ ei, float* __restrict__ out)
{
    int t = threadIdx.x;
    int l = t & 15;
    int e = blockIdx.x * 16 + (t >> 4);

    int row = ei[e];
    int col = ei[NE + e];

    float4 a = *(const float4*)&AB[(size_t)row * 128 + l * 4];
    float4 b = *(const float4*)&AB[(size_t)col * 128 + 64 + l * 4];
    float4 w = *(const float4*)&W2[l * 4];

    float h0 = fmaxf(a.x + b.x, 0.f);
    float h1 = fmaxf(a.y + b.y, 0.f);
    float h2 = fmaxf(a.z + b.z, 0.f);
    float h3 = fmaxf(a.w + b.w, 0.f);

    float p = h0 * w.x + h1 * w.y + h2 * w.z + h3 * w.w;
    p += __shfl_xor(p, 1);
    p += __shfl_xor(p, 2);
    p += __shfl_xor(p, 4);
    p += __shfl_xor(p, 8);

    if (l == 0) {
        float logit = p + b2[0];
        float u0 = u[2 * e];
        float u1 = u[2 * e + 1];
        float g0 = -logf(-logf(u0));
        float g1 = -logf(-logf(u1));
        out[e]      = (logit + g1 > g0) ? 1.0f : 0.0f;  // argmax tie -> 0
        out[NE + e] = logit;
    }
}

// ---------------------------------------------------------------------------
// Fallback (only if ws_size too small): direct per-edge compute, correct but slow.
// ---------------------------------------------------------------------------
__global__ __launch_bounds__(256)
void edge_direct(const float* __restrict__ h, const float* __restrict__ W1,
                 const float* __restrict__ b1, const float* __restrict__ W2,
                 const float* __restrict__ b2, const float* __restrict__ u,
                 const int* __restrict__ ei, float* __restrict__ out)
{
    int t = threadIdx.x;
    int l = t & 15;
    int e = blockIdx.x * 16 + (t >> 4);

    int row = ei[e];
    int col = ei[NE + e];

    float a0 = 0.f, a1 = 0.f, a2 = 0.f, a3 = 0.f;
    const float* hr = h + (size_t)row * 128;
    const float* hc = h + (size_t)col * 128;

    for (int k4 = 0; k4 < 32; ++k4) {
        float4 hv = *(const float4*)&hr[k4 * 4];
#pragma unroll
        for (int kk = 0; kk < 4; ++kk) {
            float4 wr = *(const float4*)&W1[(k4 * 4 + kk) * 64 + l * 4];
            float hval = (&hv.x)[kk];
            a0 += hval * wr.x; a1 += hval * wr.y; a2 += hval * wr.z; a3 += hval * wr.w;
        }
    }
    for (int k4 = 0; k4 < 32; ++k4) {
        float4 hv = *(const float4*)&hc[k4 * 4];
#pragma unroll
        for (int kk = 0; kk < 4; ++kk) {
            float4 wr = *(const float4*)&W1[(128 + k4 * 4 + kk) * 64 + l * 4];
            float hval = (&hv.x)[kk];
            a0 += hval * wr.x; a1 += hval * wr.y; a2 += hval * wr.z; a3 += hval * wr.w;
        }
    }
    float4 bb = *(const float4*)&b1[l * 4];
    float4 w  = *(const float4*)&W2[l * 4];
    float h0 = fmaxf(a0 + bb.x, 0.f);
    float h1 = fmaxf(a1 + bb.y, 0.f);
    float h2 = fmaxf(a2 + bb.z, 0.f);
    float h3 = fmaxf(a3 + bb.w, 0.f);

    float p = h0 * w.x + h1 * w.y + h2 * w.z + h3 * w.w;
    p += __shfl_xor(p, 1);
    p += __shfl_xor(p, 2);
    p += __shfl_xor(p, 4);
    p += __shfl_xor(p, 8);

    if (l == 0) {
        float logit = p + b2[0];
        float u0 = u[2 * e];
        float u1 = u[2 * e + 1];
        float g0 = -logf(-logf(u0));
        float g1 = -logf(-logf(u1));
        out[e]      = (logit + g1 > g0) ? 1.0f : 0.0f;
        out[NE + e] = logit;
    }
}

extern "C" void kernel_launch(void* const* d_in, const int* in_sizes, int n_in,
                              void* d_out, int out_size, void* d_ws, size_t ws_size,
                              hipStream_t stream)
{
    const float* h  = (const float*)d_in[0];
    const float* W1 = (const float*)d_in[1];
    const float* b1 = (const float*)d_in[2];
    const float* W2 = (const float*)d_in[3];
    const float* b2 = (const float*)d_in[4];
    const float* u  = (const float*)d_in[5];
    const int*   ei = (const int*)d_in[6];
    float* out = (float*)d_out;

    const size_t need = (size_t)NN * 128 * sizeof(float);   // 51.2 MB
    if (ws_size >= need) {
        float* AB = (float*)d_ws;
        int nblocks = (NN + 127) / 128;                     // 782
        node_proj<<<nblocks, 256, 0, stream>>>(h, W1, b1, AB, NN);
        edge_sample<<<NE / 16, 256, 0, stream>>>(AB, W2, b2, u, ei, out);
    } else {
        edge_direct<<<NE / 16, 256, 0, stream>>>(h, W1, b1, W2, b2, u, ei, out);
    }
}